// Round 15
// baseline (107.046 us; speedup 1.0000x reference)
//
#include <hip/hip_runtime.h>
#include <hip/hip_bf16.h>

#define NHID 64
#define NT   63
#define NBD  512
#define HLDS_STR 72   // shorts per h row (144 B): b128 reads / b64 writes 2-way (free)
#define XSTR 35       // floats per xs row

typedef __attribute__((ext_vector_type(8))) short bf16x8;
typedef __attribute__((ext_vector_type(4))) float f32x4;

__device__ __forceinline__ float tanh_fast(float x) {
    // 1 - 2/(e^{2x}+1): exact for +-large x; tanh_fast(0) == 0 bitwise
    const float e = __expf(2.0f * x);
    const float r = __builtin_amdgcn_rcpf(e + 1.0f);
    return 1.0f - 2.0f * r;
}

__device__ __forceinline__ unsigned int cvt_pk_bf16(float lo, float hi) {
    unsigned int r;
    asm("v_cvt_pk_bf16_f32 %0, %1, %2" : "=v"(r) : "v"(lo), "v"(hi));
    return r;   // lo16 = bf16(lo), hi16 = bf16(hi), RNE
}

__device__ __forceinline__ float bf2f(unsigned int u16) {
    return __uint_as_float(u16 << 16);
}

// skew-diagonal geometry (weights/k_fc only)
#define SKEW_R0(t)  ((t) > 31 ? (t) - 31 : 0)
#define SKEW_R1(t)  ((t) < 31 ? (t) : 31)
#define SKEW_OFF(t) ((t) < 32 ? ((t) * ((t) + 1)) >> 1 : 1024 - (((63 - (t)) * (64 - (t))) >> 1))

// Cross-lane LDS RAW fence: pins ds_write(step t) BEFORE ds_read(step t+1) in
// issue order (DS pipe is in-order per wave). LLVM's per-thread alias analysis
// would otherwise hoist next-step reads above this step's writes (R14 bug).
#define STEP_FENCE() do {                                     \
    asm volatile("s_waitcnt lgkmcnt(0)" ::: "memory");        \
    __builtin_amdgcn_sched_barrier(0);                        \
} while (0)

// ---------------------------------------------------------------------------
// prep helper: one 8-short B-fragment group of the swizzled w_fc
// ---------------------------------------------------------------------------
__device__ __forceinline__ void prep_one(
    const float* __restrict__ w_fc, unsigned short* __restrict__ wt_swz,
    int t, int r0, int span, int f)
{
    if (f >= 4 * span) return;
    const int fdst = f;
    int d = 0;
    while (f >= span) { f -= span; ++d; }     // <=3 iters
    const int ks   = f >> 9;
    const int lane = (f >> 3) & 63;
    const int g = lane >> 4, n = lane & 15;
    unsigned int pk[4];
    #pragma unroll
    for (int jj = 0; jj < 4; ++jj) {
        float v[2] = {0.0f, 0.0f};
        #pragma unroll
        for (int h = 0; h < 2; ++h) {
            const int j = jj * 2 + h;
            const int k = ks * 32 + g * 8 + j;
            const int r = r0 + (k >> 6);
            const int o = k & 63;
            const int c = t - r;              // guaranteed in [0,32)
            if (n < 10)
                v[h] = w_fc[((((size_t)(d * 64 + o)) << 10) + (r << 5) + c) * 10 + n];
        }
        pk[jj] = cvt_pk_bf16(v[0], v[1]);
    }
    uint4 st; st.x = pk[0]; st.y = pk[1]; st.z = pk[2]; st.w = pk[3];
    *(uint4*)(wt_swz + (size_t)SKEW_OFF(t) * 4096 + fdst) = st;
}

// ---------------------------------------------------------------------------
// k_main: blocks 0..255 = RNN, 128 threads = 2 fully INDEPENDENT waves, each
// owning one whole (dir,batch) sequence (all 64 o x 32 r). Per wave per step:
// 8 ds_read_b128 + 32 MFMA (8 independent 4-deep chains) + 32 tanh +
// 8 ds_write_b64 + masked global stores. ZERO barriers/flags; correctness
// from same-wave in-order DS + STEP_FENCE pinning issue order at each step
// boundary (cross-lane RAW is invisible to LLVM alias analysis — R14 bug).
// Blocks >= 256 = w_fc pre-swizzle (4096 blocks x 128 uint4 groups).
// acts layout: slot = bd*65536 + r*1984 + t*64 + o (bijective on valid cells).
// ---------------------------------------------------------------------------
__global__ __launch_bounds__(128, 1) void k_main(
    const float* __restrict__ x,
    const float* __restrict__ w_in,
    const float* __restrict__ b_in,
    const float* __restrict__ w_state,
    const float* __restrict__ b_state,
    unsigned short* __restrict__ acts_c,
    const float* __restrict__ w_fc,
    unsigned short* __restrict__ wt_swz)
{
    __shared__ __align__(16) unsigned short hbuf[2][33 * HLDS_STR];
    __shared__ float xs[2][32 * XSTR];

    const int tid = threadIdx.x;

    if (blockIdx.x >= 256) {
        // ---------------- w_fc pre-swizzle path ----------------
        const int rel  = blockIdx.x - 256;        // 0..4095
        const int idx4 = rel * 128 + tid;         // uint4 index, < 524288
        const int fs   = idx4 * 8;                // global short index
        const int u    = fs >> 12;                // region unit = 4096 shorts
        int t;
        if (u < 528) {
            t = (int)(0.5f * (sqrtf(8.0f * (float)u + 1.0f) - 1.0f));
        } else {
            const int w = 1024 - u;
            t = 63 - ((int)(0.5f * (sqrtf(8.0f * (float)w + 1.0f) - 1.0f)) + 1);
        }
        if (t < 0) t = 0;
        if (t > 62) t = 62;
        while (t < 62 && SKEW_OFF(t + 1) <= u) ++t;
        while (t > 0 && SKEW_OFF(t) > u) --t;
        const int r0 = SKEW_R0(t), r1 = SKEW_R1(t);
        const int span = (r1 - r0 + 1) << 10;     // shorts per d
        prep_one(w_fc, wt_swz, t, r0, span, fs - SKEW_OFF(t) * 4096);
        return;
    }

    // ---------------- RNN path: one sequence per wave ----------------
    const int wave = tid >> 6;
    const int lane = tid & 63;
    const int bd   = 2 * blockIdx.x + wave;
    const int d    = bd >> 7;
    const int b    = bd & 127;
    const int n    = lane & 15;
    const int g    = lane >> 4;

    unsigned short* h = hbuf[wave];
    float* xsw = xs[wave];

    // ---- stage x (wave-private) with direction flips ----
    const bool flr = (d & 1) != 0;
    const bool flc = (d & 2) != 0;
    const float* xb = x + (size_t)b * 1024;
    for (int idx = lane; idx < 1024; idx += 64) {
        const int r = idx >> 5, c = idx & 31;
        xsw[r * XSTR + c] = xb[(flr ? 31 - r : r) * 32 + (flc ? 31 - c : c)];
    }
    // ---- zero h buffer (row 0 = permanent zero row) ----
    for (int m2 = lane; m2 < (33 * HLDS_STR) / 2; m2 += 64)
        ((unsigned int*)h)[m2] = 0u;

    // ---- A fragments: 4 M-tiles x 4 K-tiles, single bf16 ----
    // kt: 0 = up ch 0-31, 1 = up 32-63, 2 = same 0-31, 3 = same 32-63
    bf16x8 a[4][4];
    #pragma unroll
    for (int mt = 0; mt < 4; ++mt) {
        const int o = mt * 16 + n;
        #pragma unroll
        for (int kt = 0; kt < 4; ++kt) {
            const int s  = kt >> 1;
            const int cb = (kt & 1) * 32 + g * 8;
            bf16x8 w8;
            #pragma unroll
            for (int j = 0; j < 8; ++j) {
                const float w = w_state[((size_t)o * 64 + cb + j) * 2 + s];
                w8[j] = (short)(cvt_pk_bf16(w, 0.0f) & 0xffffu);
            }
            a[mt][kt] = w8;
        }
    }

    float biasr[4][4], winr[4][4];
    #pragma unroll
    for (int mt = 0; mt < 4; ++mt)
        #pragma unroll
        for (int j = 0; j < 4; ++j) {
            const int o = mt * 16 + g * 4 + j;
            biasr[mt][j] = b_in[o] + b_state[o];
            winr[mt][j]  = w_in[o];
        }

    // N-tile 0: r = n (rows 0-15);  N-tile 1: r = 16+n (rows 16-31)
    const int rd0 = n * HLDS_STR + g * 8;             // h[r-1] row for N0
    const int rd1 = (16 + n) * HLDS_STR + g * 8;      // h[r-1] row for N1
    const int wr0 = (n + 1) * HLDS_STR + g * 4;       // h write N0
    const int wr1 = (17 + n) * HLDS_STR + g * 4;      // h write N1
    unsigned short* act0 = acts_c + (size_t)bd * 65536 + (size_t)n * 1984 + g * 4;
    unsigned short* act1 = acts_c + (size_t)bd * 65536 + (size_t)(16 + n) * 1984 + g * 4;
    int cc0 = -n;          // t - r for N0
    int cc1 = -(16 + n);   // t - r for N1
    const float* xr0 = &xsw[n * XSTR];
    const float* xr1 = &xsw[(16 + n) * XSTR];

    STEP_FENCE();   // init writes ordered before first step's reads

#define MFMA(F, B, C) C = __builtin_amdgcn_mfma_f32_16x16x32_bf16(F, B, C, 0, 0, 0)

    #pragma unroll 1
    for (int t = 0; t < NT; ++t) {
        const bf16x8 b00 = *(const bf16x8*)&h[rd0];
        const bf16x8 b01 = *(const bf16x8*)&h[rd0 + 32];
        const bf16x8 b02 = *(const bf16x8*)&h[rd0 + HLDS_STR];
        const bf16x8 b03 = *(const bf16x8*)&h[rd0 + HLDS_STR + 32];
        const bf16x8 b10 = *(const bf16x8*)&h[rd1];
        const bf16x8 b11 = *(const bf16x8*)&h[rd1 + 32];
        const bf16x8 b12 = *(const bf16x8*)&h[rd1 + HLDS_STR];
        const bf16x8 b13 = *(const bf16x8*)&h[rd1 + HLDS_STR + 32];

        f32x4 acc[4][2];
        #pragma unroll
        for (int mt = 0; mt < 4; ++mt) {
            acc[mt][0] = (f32x4){0.f, 0.f, 0.f, 0.f};
            acc[mt][1] = (f32x4){0.f, 0.f, 0.f, 0.f};
        }
        #pragma unroll
        for (int mt = 0; mt < 4; ++mt) { MFMA(a[mt][0], b00, acc[mt][0]); MFMA(a[mt][0], b10, acc[mt][1]); }
        #pragma unroll
        for (int mt = 0; mt < 4; ++mt) { MFMA(a[mt][1], b01, acc[mt][0]); MFMA(a[mt][1], b11, acc[mt][1]); }
        #pragma unroll
        for (int mt = 0; mt < 4; ++mt) { MFMA(a[mt][2], b02, acc[mt][0]); MFMA(a[mt][2], b12, acc[mt][1]); }
        #pragma unroll
        for (int mt = 0; mt < 4; ++mt) { MFMA(a[mt][3], b03, acc[mt][0]); MFMA(a[mt][3], b13, acc[mt][1]); }

        const bool st0 = (unsigned)cc0 < 32u;
        const bool st1 = (unsigned)cc1 < 32u;
        const float xv0 = st0 ? xr0[cc0 & 31] : 0.0f;
        const float xv1 = st1 ? xr1[cc1 & 31] : 0.0f;

        #pragma unroll
        for (int mt = 0; mt < 4; ++mt) {
            {   // N0
                const float h0 = tanh_fast(acc[mt][0][0] + fmaf(winr[mt][0], xv0, biasr[mt][0]));
                const float h1 = tanh_fast(acc[mt][0][1] + fmaf(winr[mt][1], xv0, biasr[mt][1]));
                const float h2 = tanh_fast(acc[mt][0][2] + fmaf(winr[mt][2], xv0, biasr[mt][2]));
                const float h3 = tanh_fast(acc[mt][0][3] + fmaf(winr[mt][3], xv0, biasr[mt][3]));
                uint2 pk; pk.x = cvt_pk_bf16(h0, h1); pk.y = cvt_pk_bf16(h2, h3);
                *(uint2*)&h[wr0 + mt * 16] = pk;
                if (st0) *(uint2*)(act0 + mt * 16) = pk;
            }
            {   // N1
                const float h0 = tanh_fast(acc[mt][1][0] + fmaf(winr[mt][0], xv1, biasr[mt][0]));
                const float h1 = tanh_fast(acc[mt][1][1] + fmaf(winr[mt][1], xv1, biasr[mt][1]));
                const float h2 = tanh_fast(acc[mt][1][2] + fmaf(winr[mt][2], xv1, biasr[mt][2]));
                const float h3 = tanh_fast(acc[mt][1][3] + fmaf(winr[mt][3], xv1, biasr[mt][3]));
                uint2 pk; pk.x = cvt_pk_bf16(h0, h1); pk.y = cvt_pk_bf16(h2, h3);
                *(uint2*)&h[wr1 + mt * 16] = pk;
                if (st1) *(uint2*)(act1 + mt * 16) = pk;
            }
        }
        act0 += 64; act1 += 64; ++cc0; ++cc1;

        STEP_FENCE();   // pin this step's ds_writes before next step's ds_reads
    }
#undef MFMA
}

// ---------------------------------------------------------------------------
// k_fc: streaming MFMA GEMM over acts. Block = (t, d, mh); 4 waves = 4 M-tiles
// of 16 batches. A pointer walks +1984 shorts per k-pair (constant stride).
// ---------------------------------------------------------------------------
__global__ __launch_bounds__(256, 4) void k_fc(
    const unsigned short* __restrict__ acts_c,
    const unsigned short* __restrict__ wt_swz,
    float* __restrict__ partial)
{
    const int tid = threadIdx.x;
    const int blk = blockIdx.x;          // 63*8
    const int t   = blk >> 3;
    const int d   = (blk >> 1) & 3;
    const int mh  = blk & 1;
    const int lane = tid & 63;
    const int wv  = tid >> 6;
    const int g   = lane >> 4;
    const int n   = lane & 15;

    const int r0 = SKEW_R0(t), r1 = SKEW_R1(t);
    const int cnt = r1 - r0 + 1;
    const int off = SKEW_OFF(t);

    const int tb = d * 128 + mh * 64 + wv * 16;
    const unsigned short* Ap = acts_c + (size_t)(tb + n) * 65536
                             + (size_t)r0 * 1984 + (size_t)t * 64 + g * 8;
    const unsigned short* Bp = wt_swz
        + ((size_t)off * 4 + (size_t)d * cnt) * 1024 + lane * 8;

    f32x4 acc = {0.f, 0.f, 0.f, 0.f};
    #pragma unroll 2
    for (int q = 0; q < cnt; ++q) {
        const bf16x8 a0  = *(const bf16x8*)(Ap);
        const bf16x8 bb0 = *(const bf16x8*)(Bp);
        const bf16x8 a1  = *(const bf16x8*)(Ap + 32);
        const bf16x8 bb1 = *(const bf16x8*)(Bp + 512);
        acc = __builtin_amdgcn_mfma_f32_16x16x32_bf16(a0, bb0, acc, 0, 0, 0);
        acc = __builtin_amdgcn_mfma_f32_16x16x32_bf16(a1, bb1, acc, 0, 0, 0);
        Ap += 1984;
        Bp += 1024;
    }
    const int batch = tb + g * 4;
    #pragma unroll
    for (int reg = 0; reg < 4; ++reg)
        partial[((size_t)t * 512 + batch + reg) * 16 + n] = acc[reg];
}

// ---------------------------------------------------------------------------
// k_out: logits[n] = b_fc[n] + sum_{t,d} partial; log_softmax.
// ---------------------------------------------------------------------------
__global__ __launch_bounds__(256) void k_out(
    const float* __restrict__ partial,
    const float* __restrict__ b_fc,
    float* __restrict__ out)
{
    __shared__ float lred[252 * 10];
    __shared__ float lgs[10];
    __shared__ float lse;
    const int b = blockIdx.x;
    const int tid = threadIdx.x;
    if (tid < 252) {
        const int t = tid >> 2, d = tid & 3;
        const float* p = partial + ((size_t)t * 512 + d * 128 + b) * 16;
        #pragma unroll
        for (int n2 = 0; n2 < 10; ++n2) lred[tid * 10 + n2] = p[n2];
    }
    __syncthreads();
    if (tid < 10) {
        float s = b_fc[tid];
        for (int i = 0; i < 252; ++i) s += lred[i * 10 + tid];
        lgs[tid] = s;
    }
    __syncthreads();
    if (tid == 0) {
        float m = lgs[0];
        for (int nn = 1; nn < 10; ++nn) m = fmaxf(m, lgs[nn]);
        float ssum = 0.0f;
        for (int nn = 0; nn < 10; ++nn) ssum += __expf(lgs[nn] - m);
        lse = m + __logf(ssum);
    }
    __syncthreads();
    if (tid < 10) out[b * 10 + tid] = lgs[tid] - lse;
}

extern "C" void kernel_launch(void* const* d_in, const int* in_sizes, int n_in,
                              void* d_out, int out_size, void* d_ws, size_t ws_size,
                              hipStream_t stream)
{
    const float* x       = (const float*)d_in[0];
    const float* w_in    = (const float*)d_in[1];
    const float* b_in    = (const float*)d_in[2];
    const float* w_state = (const float*)d_in[3];
    const float* b_state = (const float*)d_in[4];
    const float* w_fc    = (const float*)d_in[5];
    const float* b_fc    = (const float*)d_in[6];
    float* out = (float*)d_out;

    // ws layout: wt_swz 8 MiB | partial 2 MiB @8MiB | acts_c 64 MiB @16MiB
    unsigned short* wt_swz = (unsigned short*)d_ws;
    float* partial = (float*)((char*)d_ws + (size_t)(8u << 20));
    unsigned short* acts_c = (unsigned short*)((char*)d_ws + (size_t)(16u << 20));

    // blocks 0-255: RNN (2 wave-private sequences each, fence-ordered DS);
    // blocks 256-4351: w_fc pre-swizzle (concurrent)
    k_main<<<4352, 128, 0, stream>>>(x, w_in, b_in, w_state, b_state,
                                     acts_c, w_fc, wt_swz);
    k_fc  <<<504, 256, 0, stream>>>(acts_c, wt_swz, partial);
    k_out <<<128, 256, 0, stream>>>(partial, b_fc, out);
}